// Round 4
// baseline (196.332 us; speedup 1.0000x reference)
//
#include <hip/hip_runtime.h>
#include <hip/hip_bf16.h>

#define NNODES 8192
#define DIN 512
#define HD1 256
#define LATD 128

typedef __attribute__((ext_vector_type(4))) float f32x4;
typedef __attribute__((ext_vector_type(8))) short short8;

__device__ __forceinline__ float bf2f(uint u){
  union { uint i; float f; } v; v.i = u << 16; return v.f;
}
__device__ __forceinline__ ushort f2bf(float f){
  union { float f; uint i; } v; v.f = f;
  uint i = v.i;
  i += 0x7FFFu + ((i >> 16) & 1u);
  return (ushort)(i >> 16);
}

// ---------------- CSR build ----------------

// scan + dis in one kernel
__global__ __launch_bounds__(1024) void scan_kernel(const int* __restrict__ counts,
                                                    int* __restrict__ offsets,
                                                    float* __restrict__ dis){
  __shared__ int sd[1024];
  const int t = threadIdx.x;
  const int base = t * 8;
  int vals[8];
  int s = 0;
  #pragma unroll
  for (int i = 0; i < 8; ++i){ vals[i] = counts[base + i]; s += vals[i]; }
  sd[t] = s;
  __syncthreads();
  for (int off = 1; off < 1024; off <<= 1){
    int x = (t >= off) ? sd[t - off] : 0;
    __syncthreads();
    sd[t] += x;
    __syncthreads();
  }
  int ex = sd[t] - s;
  #pragma unroll
  for (int i = 0; i < 8; ++i){
    offsets[base + i] = ex; ex += vals[i];
    // deg = in-degree + 2 (self-loop added in forward + again by gcn_norm)
    dis[base + i] = rsqrtf((float)(vals[i] + 2));
  }
  if (t == 1023) offsets[8192] = ex;
}

__global__ void fill_csr(const int* __restrict__ erow, const int* __restrict__ ecol,
                         const int* __restrict__ offsets, int* __restrict__ cursor,
                         int* __restrict__ csr, int E){
  int e = blockIdx.x * 256 + threadIdx.x;
  if (e >= E) return;
  int r = erow[e], c = ecol[e];
  int pos = atomicAdd(&cursor[c], 1);
  csr[offsets[c] + pos] = r;
}

// ---------------- GEMM body: C[M,N] = A[M,K] @ B_f32[K,N], bf16 out ----------------
// 64x64 tile, BK=32, 4 waves of 32x32, mfma 16x16x32 bf16. A is f32 or bf16.

template<bool AF32>
__device__ __forceinline__ void gemm_body(const void* __restrict__ Av,
    const float* __restrict__ B, ushort* __restrict__ Cb,
    int n0, int m0, int N, int K)
{
  __shared__ ushort Al[64][40];
  __shared__ ushort Bl[64][40];   // stored transposed: Bl[n][k]
  const int t = threadIdx.x;
  const int wid = t >> 6, l = t & 63, lr = l & 15, lk = l >> 4;
  const int wm = (wid >> 1) * 32, wn = (wid & 1) * 32;
  f32x4 acc[2][2] = {};
  const int nkt = K >> 5;
  for (int kt = 0; kt < nkt; ++kt){
    {
      const int row = t >> 2, ch = t & 3;
      if (AF32){
        const float* ap = (const float*)Av + (size_t)(m0 + row) * K + kt * 32 + ch * 8;
        float4 v0 = *(const float4*)ap;
        float4 v1 = *(const float4*)(ap + 4);
        ushort* d = &Al[row][ch * 8];
        d[0] = f2bf(v0.x); d[1] = f2bf(v0.y); d[2] = f2bf(v0.z); d[3] = f2bf(v0.w);
        d[4] = f2bf(v1.x); d[5] = f2bf(v1.y); d[6] = f2bf(v1.z); d[7] = f2bf(v1.w);
      } else {
        *(short8*)(&Al[row][ch * 8]) =
          *(const short8*)((const ushort*)Av + (size_t)(m0 + row) * K + kt * 32 + ch * 8);
      }
      const int kk = t >> 3, nn = (t & 7) * 8;
      const float* bp = B + (size_t)(kt * 32 + kk) * N + n0 + nn;
      float4 v0 = *(const float4*)bp;
      float4 v1 = *(const float4*)(bp + 4);
      Bl[nn + 0][kk] = f2bf(v0.x); Bl[nn + 1][kk] = f2bf(v0.y);
      Bl[nn + 2][kk] = f2bf(v0.z); Bl[nn + 3][kk] = f2bf(v0.w);
      Bl[nn + 4][kk] = f2bf(v1.x); Bl[nn + 5][kk] = f2bf(v1.y);
      Bl[nn + 6][kk] = f2bf(v1.z); Bl[nn + 7][kk] = f2bf(v1.w);
    }
    __syncthreads();
    short8 a0 = *(const short8*)(&Al[wm + lr][lk * 8]);
    short8 a1 = *(const short8*)(&Al[wm + 16 + lr][lk * 8]);
    short8 b0 = *(const short8*)(&Bl[wn + lr][lk * 8]);
    short8 b1 = *(const short8*)(&Bl[wn + 16 + lr][lk * 8]);
    acc[0][0] = __builtin_amdgcn_mfma_f32_16x16x32_bf16(a0, b0, acc[0][0], 0, 0, 0);
    acc[0][1] = __builtin_amdgcn_mfma_f32_16x16x32_bf16(a0, b1, acc[0][1], 0, 0, 0);
    acc[1][0] = __builtin_amdgcn_mfma_f32_16x16x32_bf16(a1, b0, acc[1][0], 0, 0, 0);
    acc[1][1] = __builtin_amdgcn_mfma_f32_16x16x32_bf16(a1, b1, acc[1][1], 0, 0, 0);
    __syncthreads();
  }
  #pragma unroll
  for (int mi = 0; mi < 2; ++mi){
    #pragma unroll
    for (int ni = 0; ni < 2; ++ni){
      const int row = m0 + wm + mi * 16 + lk * 4;
      const int col = n0 + wn + ni * 16 + lr;
      #pragma unroll
      for (int r = 0; r < 4; ++r)
        Cb[(size_t)(row + r) * N + col] = f2bf(acc[mi][ni][r]);
    }
  }
}

// fused: blocks [0, nbCnt) do degree count; blocks [nbCnt, ...) do gemm1 (x f32 @ W1)
__global__ __launch_bounds__(256) void k_count_gemm1(const int* __restrict__ ecol,
    int* __restrict__ counts, int E, int nbCnt,
    const float* __restrict__ x, const float* __restrict__ W1, ushort* __restrict__ h1)
{
  if ((int)blockIdx.x < nbCnt){
    int e = blockIdx.x * 256 + threadIdx.x;
    if (e < E) atomicAdd(&counts[ecol[e]], 1);
    return;
  }
  const int bx = blockIdx.x - nbCnt;
  const int n0 = (bx & 3) * 64;           // HD1/64 = 4 column blocks
  const int m0 = (bx >> 2) * 64;
  gemm_body<true>(x, W1, h1, n0, m0, HD1, DIN);
}

__global__ __launch_bounds__(256) void gemm2_kernel(const ushort* __restrict__ A,
    const float* __restrict__ B, ushort* __restrict__ Cb)
{
  gemm_body<false>(A, B, Cb, blockIdx.x * 64, blockIdx.y * 64, LATD, HD1);
}

// ---------------- fused mu/logvar GEMM: K=N=128, block-uniform B select ----------------

__global__ __launch_bounds__(256) void gemm_mulv(const ushort* __restrict__ A,
    const float* __restrict__ Wmu, const float* __restrict__ bmu,
    const float* __restrict__ Wlv, const float* __restrict__ blv,
    float* __restrict__ mu, ushort* __restrict__ mu_bf, float* __restrict__ lv)
{
  __shared__ ushort Al[64][40];
  __shared__ ushort Bl[64][40];
  const int t = threadIdx.x;
  const int gn0 = blockIdx.x * 64, m0 = blockIdx.y * 64;
  const bool is_mu = gn0 < LATD;
  const float* B = is_mu ? Wmu : Wlv;
  const float* bias = is_mu ? bmu : blv;
  const int n0 = gn0 & (LATD - 1);
  const int wid = t >> 6, l = t & 63, lr = l & 15, lk = l >> 4;
  const int wm = (wid >> 1) * 32, wn = (wid & 1) * 32;
  f32x4 acc[2][2] = {};
  for (int kt = 0; kt < LATD / 32; ++kt){
    {
      const int row = t >> 2, ch = t & 3;
      *(short8*)(&Al[row][ch * 8]) =
        *(const short8*)(A + (size_t)(m0 + row) * LATD + kt * 32 + ch * 8);
      const int kk = t >> 3, nn = (t & 7) * 8;
      const float* bp = B + (size_t)(kt * 32 + kk) * LATD + n0 + nn;
      float4 v0 = *(const float4*)bp;
      float4 v1 = *(const float4*)(bp + 4);
      Bl[nn + 0][kk] = f2bf(v0.x); Bl[nn + 1][kk] = f2bf(v0.y);
      Bl[nn + 2][kk] = f2bf(v0.z); Bl[nn + 3][kk] = f2bf(v0.w);
      Bl[nn + 4][kk] = f2bf(v1.x); Bl[nn + 5][kk] = f2bf(v1.y);
      Bl[nn + 6][kk] = f2bf(v1.z); Bl[nn + 7][kk] = f2bf(v1.w);
    }
    __syncthreads();
    short8 a0 = *(const short8*)(&Al[wm + lr][lk * 8]);
    short8 a1 = *(const short8*)(&Al[wm + 16 + lr][lk * 8]);
    short8 b0 = *(const short8*)(&Bl[wn + lr][lk * 8]);
    short8 b1 = *(const short8*)(&Bl[wn + 16 + lr][lk * 8]);
    acc[0][0] = __builtin_amdgcn_mfma_f32_16x16x32_bf16(a0, b0, acc[0][0], 0, 0, 0);
    acc[0][1] = __builtin_amdgcn_mfma_f32_16x16x32_bf16(a0, b1, acc[0][1], 0, 0, 0);
    acc[1][0] = __builtin_amdgcn_mfma_f32_16x16x32_bf16(a1, b0, acc[1][0], 0, 0, 0);
    acc[1][1] = __builtin_amdgcn_mfma_f32_16x16x32_bf16(a1, b1, acc[1][1], 0, 0, 0);
    __syncthreads();
  }
  #pragma unroll
  for (int mi = 0; mi < 2; ++mi){
    #pragma unroll
    for (int ni = 0; ni < 2; ++ni){
      const int row = m0 + wm + mi * 16 + lk * 4;
      const int col = n0 + wn + ni * 16 + lr;
      float bb = bias[col];
      #pragma unroll
      for (int r = 0; r < 4; ++r){
        float v = acc[mi][ni][r] + bb;
        if (is_mu){
          mu[(size_t)(row + r) * LATD + col] = v;
          mu_bf[(size_t)(row + r) * LATD + col] = f2bf(v);
        } else {
          lv[(size_t)(row + r) * LATD + col] = v;
        }
      }
    }
  }
}

// ---------------- aggregation v2 ----------------
// One node per wave. Per 64-edge chunk: lanes prefetch (idx, norm) to LDS meta,
// then the wave gathers EPI edges per iteration (each lane: 16B = 8 bf16 of one
// edge's row), partial sums across lane sub-groups combined by shfl_xor.

template<int F, bool RELU>
__global__ __launch_bounds__(256) void agg_kernel(const ushort* __restrict__ h,
    const float* __restrict__ bias, const int* __restrict__ offsets,
    const int* __restrict__ csr, const float* __restrict__ dis,
    ushort* __restrict__ out)
{
  constexpr int LPE = F / 8;      // lanes per edge (32 for F=256, 16 for F=128)
  constexpr int EPI = 64 / LPE;   // edges per iteration
  __shared__ int2 meta[4][64];
  const int w = threadIdx.x >> 6, l = threadIdx.x & 63;
  const int v = blockIdx.x * 4 + w;
  const float dv = dis[v];
  const int sub = l / LPE;
  const int eb = (l % LPE) * 8;   // element base within the row
  float acc[8] = {0.f, 0.f, 0.f, 0.f, 0.f, 0.f, 0.f, 0.f};

  const int beg = offsets[v], end = offsets[v + 1];
  for (int base = beg; base < end; base += 64){
    const int cnt = min(64, end - base);
    int idx = 0; float nr = 0.f;
    if (base + l < end){ idx = csr[base + l]; nr = dis[idx] * dv; }
    int2 m; m.x = idx; m.y = __float_as_int(nr);
    meta[w][l] = m;
    asm volatile("s_waitcnt lgkmcnt(0)" ::: "memory");
    const int nIt = (cnt + EPI - 1) / EPI;
    for (int it = 0; it < nIt; ++it){
      int2 mm = meta[w][it * EPI + sub];
      const float nrr = __int_as_float(mm.y);
      const uint4 r = *(const uint4*)(h + (size_t)mm.x * F + eb);
      acc[0] += nrr * bf2f(r.x & 0xffff); acc[1] += nrr * bf2f(r.x >> 16);
      acc[2] += nrr * bf2f(r.y & 0xffff); acc[3] += nrr * bf2f(r.y >> 16);
      acc[4] += nrr * bf2f(r.z & 0xffff); acc[5] += nrr * bf2f(r.z >> 16);
      acc[6] += nrr * bf2f(r.w & 0xffff); acc[7] += nrr * bf2f(r.w >> 16);
    }
    asm volatile("s_waitcnt lgkmcnt(0)" ::: "memory");  // reads done before next chunk's writes
  }
  // combine sub-group partials
  #pragma unroll
  for (int off = LPE; off < 64; off <<= 1){
    #pragma unroll
    for (int j = 0; j < 8; ++j) acc[j] += __shfl_xor(acc[j], off);
  }
  if (l < LPE){
    const float ss = 2.f * dv * dv;
    const uint4 r = *(const uint4*)(h + (size_t)v * F + eb);
    acc[0] += ss * bf2f(r.x & 0xffff); acc[1] += ss * bf2f(r.x >> 16);
    acc[2] += ss * bf2f(r.y & 0xffff); acc[3] += ss * bf2f(r.y >> 16);
    acc[4] += ss * bf2f(r.z & 0xffff); acc[5] += ss * bf2f(r.z >> 16);
    acc[6] += ss * bf2f(r.w & 0xffff); acc[7] += ss * bf2f(r.w >> 16);
    float4 b0 = *(const float4*)(bias + eb);
    float4 b1 = *(const float4*)(bias + eb + 4);
    acc[0] += b0.x; acc[1] += b0.y; acc[2] += b0.z; acc[3] += b0.w;
    acc[4] += b1.x; acc[5] += b1.y; acc[6] += b1.z; acc[7] += b1.w;
    if (RELU){
      #pragma unroll
      for (int j = 0; j < 8; ++j) acc[j] = fmaxf(acc[j], 0.f);
    }
    uint4 o;
    o.x = (uint)f2bf(acc[0]) | ((uint)f2bf(acc[1]) << 16);
    o.y = (uint)f2bf(acc[2]) | ((uint)f2bf(acc[3]) << 16);
    o.z = (uint)f2bf(acc[4]) | ((uint)f2bf(acc[5]) << 16);
    o.w = (uint)f2bf(acc[6]) | ((uint)f2bf(acc[7]) << 16);
    *(uint4*)(out + (size_t)v * F + eb) = o;
  }
}

// ---------------- adj = sigmoid(mu @ mu^T), 128x128 tiles, f32 out ----------------

__global__ __launch_bounds__(512) void gemm5_kernel(const ushort* __restrict__ mu,
                                                    float* __restrict__ adj)
{
  __shared__ char lds[65536];
  const int t = threadIdx.x;
  const int bj = blockIdx.x, bi = blockIdx.y;
  {
    const int row = t >> 2, ch = t & 3;
    const char* srcA = (const char*)(mu + (size_t)(bi * 128 + row) * LATD);
    const char* srcB = (const char*)(mu + (size_t)(bj * 128 + row) * LATD);
    char* dA = lds + row * 256;
    char* dB = lds + 32768 + row * 256;
    #pragma unroll
    for (int i = 0; i < 4; ++i){
      const int kb = ch * 64 + i * 16;
      const int sk = kb ^ ((row & 7) << 4);
      *(short8*)(dA + sk) = *(const short8*)(srcA + kb);
      *(short8*)(dB + sk) = *(const short8*)(srcB + kb);
    }
  }
  __syncthreads();
  const int wid = t >> 6, l = t & 63, lr = l & 15, lk = l >> 4;
  const int wm = (wid >> 2) * 64, wn = (wid & 3) * 32;
  f32x4 acc[4][2] = {};
  #pragma unroll
  for (int ks = 0; ks < 4; ++ks){
    short8 a[4], b[2];
    const int kb = ks * 64 + lk * 16;
    #pragma unroll
    for (int mi = 0; mi < 4; ++mi){
      const int r = wm + mi * 16 + lr;
      a[mi] = *(const short8*)(lds + r * 256 + (kb ^ ((r & 7) << 4)));
    }
    #pragma unroll
    for (int ni = 0; ni < 2; ++ni){
      const int r = wn + ni * 16 + lr;
      b[ni] = *(const short8*)(lds + 32768 + r * 256 + (kb ^ ((r & 7) << 4)));
    }
    #pragma unroll
    for (int mi = 0; mi < 4; ++mi)
      #pragma unroll
      for (int ni = 0; ni < 2; ++ni)
        acc[mi][ni] = __builtin_amdgcn_mfma_f32_16x16x32_bf16(a[mi], b[ni], acc[mi][ni], 0, 0, 0);
  }
  // direct store epilogue: sigmoid on the fly
  float* orow = adj + (size_t)(bi * 128 + wm + lk * 4) * NNODES + bj * 128 + wn + lr;
  #pragma unroll
  for (int mi = 0; mi < 4; ++mi){
    #pragma unroll
    for (int ni = 0; ni < 2; ++ni){
      #pragma unroll
      for (int r = 0; r < 4; ++r){
        const float x = acc[mi][ni][r];
        orow[(size_t)(mi * 16 + r) * NNODES + ni * 16] = 1.f / (1.f + __expf(-x));
      }
    }
  }
}

// ---------------- launch ----------------

extern "C" void kernel_launch(void* const* d_in, const int* in_sizes, int n_in,
                              void* d_out, int out_size, void* d_ws, size_t ws_size,
                              hipStream_t stream)
{
  const float* x    = (const float*)d_in[0];
  const int*   ei   = (const int*)d_in[1];
  const float* W1   = (const float*)d_in[2];
  const float* b1   = (const float*)d_in[3];
  const float* W2   = (const float*)d_in[4];
  const float* b2   = (const float*)d_in[5];
  const float* Wmu  = (const float*)d_in[6];
  const float* bmu  = (const float*)d_in[7];
  const float* Wlv  = (const float*)d_in[8];
  const float* blv  = (const float*)d_in[9];
  const int E = in_sizes[1] / 2;
  const int* erow = ei;
  const int* ecol = ei + E;

  char* ws = (char*)d_ws;
  int*    counts  = (int*)(ws);                  // 32KB
  int*    cursor  = (int*)(ws + 32768);          // 32KB
  int*    offsets = (int*)(ws + 65536);          // 8193 ints
  float*  dis     = (float*)(ws + 102400);       // 32KB
  int*    csr     = (int*)(ws + 135168);         // ~1MB
  ushort* h1      = (ushort*)(ws + 2097152);     // 4MB (8192x256)
  ushort* z1      = (ushort*)(ws + 6291456);     // 4MB
  ushort* h2      = (ushort*)(ws + 10485760);    // 2MB (8192x128)
  ushort* z2      = (ushort*)(ws + 12582912);    // 2MB
  ushort* mu_bf   = (ushort*)(ws + 14680064);    // 2MB

  float* adj = (float*)d_out;
  float* mu  = adj + (size_t)NNODES * NNODES;
  float* lv  = mu + (size_t)NNODES * LATD;

  const int nbCnt = (E + 255) / 256;

  hipMemsetAsync(d_ws, 0, 65536, stream);  // counts + cursor
  // fused: degree count + gemm1 (h1 = x @ W1, f32 A staged to bf16)
  k_count_gemm1<<<nbCnt + (HD1 / 64) * (NNODES / 64), 256, 0, stream>>>(
      ecol, counts, E, nbCnt, x, W1, h1);
  scan_kernel<<<1, 1024, 0, stream>>>(counts, offsets, dis);
  fill_csr<<<nbCnt, 256, 0, stream>>>(erow, ecol, offsets, cursor, csr, E);

  // z1 = relu(agg(h1) + b1)
  agg_kernel<HD1, true><<<NNODES / 4, 256, 0, stream>>>(h1, b1, offsets, csr, dis, z1);
  // h2 = z1 @ W2
  gemm2_kernel<<<dim3(LATD / 64, NNODES / 64), 256, 0, stream>>>(z1, W2, h2);
  // z2 = agg(h2) + b2
  agg_kernel<LATD, false><<<NNODES / 4, 256, 0, stream>>>(h2, b2, offsets, csr, dis, z2);
  // mu (f32 + bf16) / logvar (f32)
  gemm_mulv<<<dim3(2 * LATD / 64, NNODES / 64), 256, 0, stream>>>(z2, Wmu, bmu, Wlv, blv, mu, mu_bf, lv);

  // adj = sigmoid(mu @ mu^T) — launched TWICE on purpose (idempotent probe):
  // next round removes the duplicate; the dur delta measures gemm5's true cost.
  gemm5_kernel<<<dim3(NNODES / 128, NNODES / 128), 512, 0, stream>>>(mu_bf, adj);
  gemm5_kernel<<<dim3(NNODES / 128, NNODES / 128), 512, 0, stream>>>(mu_bf, adj);
}